// Round 11
// baseline (692.439 us; speedup 1.0000x reference)
//
#include <hip/hip_runtime.h>
#include <hip/hip_cooperative_groups.h>
#include <math.h>

namespace cg = cooperative_groups;

typedef _Float16 half8v __attribute__((ext_vector_type(8)));
typedef float    f32x4  __attribute__((ext_vector_type(4)));

#define DSTR 16   // degree-counter stride (ints): 1 counter per 64B line

// ---------------------------------------------------------------------------
// GCN 3-layer forward:  h = relu(Ahat @ (x @ W) + b)  x3
// Ahat = D^-1/2 (A + I) D^-1/2, CSR-by-dst, rows padded to x4, entries packed
// u32 {col:16 | w_fp16:16}. ALL preprocessing (zero, histogram+slot, 3-phase
// scan, fill, weight cvt) fused in ONE cooperative kernel (grid.sync between
// phases) - removes 6 dispatch gaps + the deg memset. GEMMs on
// mfma_f32_16x16x32_f16 with B in LDS; H fp16 between layers; half8 gathers.
// ---------------------------------------------------------------------------

__global__ __launch_bounds__(256) void preproc_kernel(
    const int* __restrict__ ei, int E, int n,
    int* __restrict__ deg, int* __restrict__ pos, int* __restrict__ row_ptr,
    int* __restrict__ partial, float* __restrict__ dinv, unsigned* __restrict__ csr,
    const float* __restrict__ W1, const float* __restrict__ W2,
    const float* __restrict__ W3,
    _Float16* __restrict__ Bt1, _Float16* __restrict__ Bt2,
    _Float16* __restrict__ Bt3)
{
    cg::grid_group grid = cg::this_grid();
    __shared__ int s[256];
    const int ltid = threadIdx.x;
    const int tid  = blockIdx.x * 256 + ltid;
    const int nth  = gridDim.x * 256;
    const int* dstp = ei + E;

    // ---- phase 0: zero used deg slots + weight convert/transpose ----------
    for (int i = tid; i < n; i += nth) deg[(size_t)i * DSTR] = 0;
    const int w1e = 256 * 128, w2e = w1e + 128 * 128, w3e = w2e + 128 * 64;
    for (int i = tid; i < w3e; i += nth) {
        if (i < w1e)      { int k = i & 255, nn = i >> 8;           Bt1[i] = (_Float16)W1[(size_t)k * 128 + nn]; }
        else if (i < w2e) { int j = i - w1e; int k = j & 127, nn = j >> 7; Bt2[j] = (_Float16)W2[(size_t)k * 128 + nn]; }
        else              { int j = i - w2e; int k = j & 127, nn = j >> 7; Bt3[j] = (_Float16)W3[(size_t)k * 64 + nn]; }
    }
    grid.sync();

    // ---- phase 1: degree histogram + slot positions (padded counters) -----
    for (int i = tid; i < E; i += nth)
        pos[i] = atomicAdd(&deg[(size_t)dstp[i] * DSTR], 1);
    grid.sync();

    // ---- phase 2: per-256-chunk scan of padded row sizes; emits dinv ------
    int nb = (n + 255) >> 8;
    for (int c = blockIdx.x; c < nb; c += gridDim.x) {
        int i = (c << 8) + ltid;
        int dg = (i < n) ? deg[(size_t)i * DSTR] : 0;
        if (i < n) dinv[i] = 1.0f / sqrtf((float)(dg + 1));   // +1 self-loop
        int v = (i < n) ? ((dg + 4) & ~3) : 0;                // (deg+1) -> x4
        s[ltid] = v;
        __syncthreads();
        #pragma unroll
        for (int off = 1; off < 256; off <<= 1) {
            int t = (ltid >= off) ? s[ltid - off] : 0;
            __syncthreads();
            s[ltid] += t;
            __syncthreads();
        }
        if (i < n) row_ptr[i + 1] = s[ltid];
        if (ltid == 255) partial[c] = s[255];
        __syncthreads();
    }
    grid.sync();

    // ---- phase 3: exclusive scan of block partials (block 0; nb<=256) -----
    if (blockIdx.x == 0) {
        int v = (ltid < nb) ? partial[ltid] : 0;
        s[ltid] = v;
        __syncthreads();
        #pragma unroll
        for (int off = 1; off < 256; off <<= 1) {
            int t = (ltid >= off) ? s[ltid - off] : 0;
            __syncthreads();
            s[ltid] += t;
            __syncthreads();
        }
        if (ltid < nb) partial[ltid] = s[ltid] - v;
    }
    grid.sync();

    // ---- phase 4: add back partials; finalize row_ptr ----------------------
    if (tid == 0) row_ptr[0] = 0;
    for (int i = tid; i < n; i += nth) row_ptr[i + 1] += partial[i >> 8];
    grid.sync();

    // ---- phase 5: fill CSR (edges + self-loops + explicit pad slots) -------
    int total = E + n + 3 * n;
    for (int idx = tid; idx < total; idx += nth) {
        int sn, d, slot;
        if (idx < E)          { sn = ei[idx]; d = dstp[idx]; slot = pos[idx]; }
        else if (idx < E + n) { sn = d = idx - E; slot = deg[(size_t)d * DSTR]; }
        else {
            int p = idx - E - n;
            int dd = p / 3, pi = p - dd * 3;
            int dg = deg[(size_t)dd * DSTR];
            int real = dg + 1;
            int padded = (dg + 4) & ~3;
            if (pi < padded - real) csr[row_ptr[dd] + real + pi] = 0u;
            continue;
        }
        float w = dinv[sn] * dinv[d];
        union { _Float16 h; unsigned short u; } cv; cv.h = (_Float16)w;
        csr[row_ptr[d] + slot] = (unsigned)sn | ((unsigned)cv.u << 16);
    }
}

// ---------------------------------------------------------------------------
// MFMA GEMM: C[M,TNv](fp16) = A[M,K] @ Bt[TNv,K]^T.  K,TNv compile-time.
// 256 threads = 4 waves x 32 rows = 128 rows/block.
// B staged ONCE into LDS (padded stride KP=K+8 halves -> 2-way banks, free).
// Fragments (16x16x32 f16):
//   A reg j: A[row=lane&15][k=(lane>>4)*8+j]
//   B reg j: B[k=(lane>>4)*8+j][col=lane&15]   from Bt[col][k]
//   D reg j: D[row=(lane>>4)*4+j][col=lane&15] (m89/m91-verified)
// ---------------------------------------------------------------------------
template <typename TA, int K, int TNv>
__global__ __launch_bounds__(256) void mfma_gemm_kernel(const TA* __restrict__ A,
                                                        const _Float16* __restrict__ Bt,
                                                        _Float16* __restrict__ C,
                                                        int M) {
    constexpr int NF = TNv / 16;
    constexpr int KP = K + 8;                      // padded row stride (halves)
    constexpr int CHUNKS = (TNv * (K / 8)) / 256;  // 16B chunks per thread
    __shared__ _Float16 Bs[TNv * KP];

    int tid = threadIdx.x;
    #pragma unroll
    for (int i = 0; i < CHUNKS; ++i) {
        int id = tid + i * 256;
        int n  = id / (K / 8);
        int k8 = (id % (K / 8)) * 8;
        *(half8v*)(&Bs[n * KP + k8]) = *(const half8v*)(Bt + (size_t)n * K + k8);
    }
    __syncthreads();

    int lane = tid & 63;
    int wave = tid >> 6;
    int r  = lane & 15;
    int kg = lane >> 4;
    int row0 = blockIdx.x * 128 + wave * 32;

    f32x4 acc[2][NF];
    #pragma unroll
    for (int mf = 0; mf < 2; ++mf)
        #pragma unroll
        for (int nf = 0; nf < NF; ++nf)
            acc[mf][nf] = (f32x4){0.f, 0.f, 0.f, 0.f};

    int rowA0 = row0 + r;      if (rowA0 > M - 1) rowA0 = M - 1;
    int rowA1 = row0 + 16 + r; if (rowA1 > M - 1) rowA1 = M - 1;
    const TA* pa0 = A + (size_t)rowA0 * K + kg * 8;
    const TA* pa1 = A + (size_t)rowA1 * K + kg * 8;

    #pragma unroll
    for (int kc = 0; kc < K; kc += 32) {
        half8v a0, a1;
        if constexpr (__is_same(TA, float)) {
            float4 l0 = *(const float4*)(pa0 + kc);
            float4 h0 = *(const float4*)(pa0 + kc + 4);
            float4 l1 = *(const float4*)(pa1 + kc);
            float4 h1 = *(const float4*)(pa1 + kc + 4);
            a0[0] = (_Float16)l0.x; a0[1] = (_Float16)l0.y; a0[2] = (_Float16)l0.z; a0[3] = (_Float16)l0.w;
            a0[4] = (_Float16)h0.x; a0[5] = (_Float16)h0.y; a0[6] = (_Float16)h0.z; a0[7] = (_Float16)h0.w;
            a1[0] = (_Float16)l1.x; a1[1] = (_Float16)l1.y; a1[2] = (_Float16)l1.z; a1[3] = (_Float16)l1.w;
            a1[4] = (_Float16)h1.x; a1[5] = (_Float16)h1.y; a1[6] = (_Float16)h1.z; a1[7] = (_Float16)h1.w;
        } else {
            a0 = *(const half8v*)(pa0 + kc);
            a1 = *(const half8v*)(pa1 + kc);
        }
        #pragma unroll
        for (int nf = 0; nf < NF; ++nf) {
            half8v b = *(const half8v*)(&Bs[(nf * 16 + r) * KP + kc + kg * 8]);
            acc[0][nf] = __builtin_amdgcn_mfma_f32_16x16x32_f16(a0, b, acc[0][nf], 0, 0, 0);
            acc[1][nf] = __builtin_amdgcn_mfma_f32_16x16x32_f16(a1, b, acc[1][nf], 0, 0, 0);
        }
    }

    #pragma unroll
    for (int mf = 0; mf < 2; ++mf) {
        #pragma unroll
        for (int j = 0; j < 4; ++j) {
            int row = row0 + mf * 16 + kg * 4 + j;
            if (row < M) {
                #pragma unroll
                for (int nf = 0; nf < NF; ++nf)
                    C[(size_t)row * TNv + nf * 16 + r] = (_Float16)acc[mf][nf][j];
            }
        }
    }
}

// ---------------------------------------------------------------------------
// SpMM + bias + relu, fp16 H, rows padded to x4, packed u32 CSR.
// One wave per node; half8 (16B) gathers, row split over LPR lanes.
// Batches: 16 edges (U16 in flight) / 8 / 4 tails.
// ---------------------------------------------------------------------------
template <int F, typename TOut>
__global__ __launch_bounds__(256) void spmm_kernel(const _Float16* __restrict__ H,
                                                   const int* __restrict__ row_ptr,
                                                   const unsigned* __restrict__ csr,
                                                   const float* __restrict__ bias,
                                                   TOut* __restrict__ out,
                                                   int n_nodes) {
    constexpr int LPR = F / 8;       // lanes per row: 16 (F=128) / 8 (F=64)
    constexpr int RPW = 64 / LPR;    // rows per gather instr: 4 / 8
    constexpr int U16 = 16 / RPW;    // in flight, 16-edge batch: 4 / 2
    constexpr int U8  = 8 / RPW;     // in flight, 8-edge batch: 2 / 1
    int wave = threadIdx.x >> 6;
    int lane = threadIdx.x & 63;
    int node = (blockIdx.x << 2) + wave;
    if (node >= n_nodes) return;

    int h  = lane / LPR;             // edge slot group (0..RPW-1)
    int fi = (lane % LPR) * 8;       // feature offset (halves)
    const _Float16* Hf = H + fi;

    int e0 = row_ptr[node];
    int e1 = row_ptr[node + 1];

    float acc[U16][8];
    #pragma unroll
    for (int i = 0; i < U16; ++i)
        #pragma unroll
        for (int j = 0; j < 8; ++j) acc[i][j] = 0.f;

    auto unpack_w = [](unsigned pk) -> float {
        union { unsigned short u; _Float16 h; } cv;
        cv.u = (unsigned short)(pk >> 16);
        return (float)cv.h;
    };

    int e = e0;
    for (; e + 16 <= e1; e += 16) {
        unsigned pk[U16];
        #pragma unroll
        for (int i = 0; i < U16; ++i) pk[i] = csr[e + i * RPW + h];
        #pragma unroll
        for (int i = 0; i < U16; ++i) {
            half8v v = *(const half8v*)(Hf + (size_t)(pk[i] & 0xFFFFu) * F);
            float w = unpack_w(pk[i]);
            #pragma unroll
            for (int j = 0; j < 8; ++j) acc[i][j] = fmaf(w, (float)v[j], acc[i][j]);
        }
    }
    if (e + 8 <= e1) {
        unsigned pk[U8];
        #pragma unroll
        for (int i = 0; i < U8; ++i) pk[i] = csr[e + i * RPW + h];
        #pragma unroll
        for (int i = 0; i < U8; ++i) {
            half8v v = *(const half8v*)(Hf + (size_t)(pk[i] & 0xFFFFu) * F);
            float w = unpack_w(pk[i]);
            #pragma unroll
            for (int j = 0; j < 8; ++j) acc[i][j] = fmaf(w, (float)v[j], acc[i][j]);
        }
        e += 8;
    }
    if (e < e1) {   // exactly 4 remaining (rows padded to x4)
        unsigned pk = (RPW == 4 || h < 4) ? csr[e + h] : 0u;
        half8v v = *(const half8v*)(Hf + (size_t)(pk & 0xFFFFu) * F);
        float w = unpack_w(pk);
        #pragma unroll
        for (int j = 0; j < 8; ++j) acc[0][j] = fmaf(w, (float)v[j], acc[0][j]);
    }

    float t[8];
    #pragma unroll
    for (int j = 0; j < 8; ++j) {
        t[j] = acc[0][j];
        #pragma unroll
        for (int i = 1; i < U16; ++i) t[j] += acc[i][j];
    }
    #pragma unroll
    for (int off = LPR; off < 64; off <<= 1)
        #pragma unroll
        for (int j = 0; j < 8; ++j) t[j] += __shfl_xor(t[j], off);

    if (h == 0) {
        float4 bl = *(const float4*)(bias + fi);
        float4 bh = *(const float4*)(bias + fi + 4);
        float o[8];
        o[0] = fmaxf(t[0] + bl.x, 0.f); o[1] = fmaxf(t[1] + bl.y, 0.f);
        o[2] = fmaxf(t[2] + bl.z, 0.f); o[3] = fmaxf(t[3] + bl.w, 0.f);
        o[4] = fmaxf(t[4] + bh.x, 0.f); o[5] = fmaxf(t[5] + bh.y, 0.f);
        o[6] = fmaxf(t[6] + bh.z, 0.f); o[7] = fmaxf(t[7] + bh.w, 0.f);
        if constexpr (__is_same(TOut, _Float16)) {
            half8v hv;
            #pragma unroll
            for (int j = 0; j < 8; ++j) hv[j] = (_Float16)o[j];
            *(half8v*)(out + (size_t)node * F + fi) = hv;
        } else {
            *(float4*)(out + (size_t)node * F + fi)     = make_float4(o[0], o[1], o[2], o[3]);
            *(float4*)(out + (size_t)node * F + fi + 4) = make_float4(o[4], o[5], o[6], o[7]);
        }
    }
}

// ---------------------------------------------------------------------------

extern "C" void kernel_launch(void* const* d_in, const int* in_sizes, int n_in,
                              void* d_out, int out_size, void* d_ws, size_t ws_size,
                              hipStream_t stream) {
    const float* x  = (const float*)d_in[0];
    const int*   ei = (const int*)d_in[1];     // [2, E] int32
    const float* W1 = (const float*)d_in[2];
    const float* b1 = (const float*)d_in[3];
    const float* W2 = (const float*)d_in[4];
    const float* b2 = (const float*)d_in[5];
    const float* W3 = (const float*)d_in[6];
    const float* b3 = (const float*)d_in[7];

    const int IN_DIM = 256, HID = 128, OUT = 64;
    int n_nodes = in_sizes[0] / IN_DIM;    // 50000 (< 65536 required for u32 pack)
    int n_edges = in_sizes[1] / 2;         // 800000
    int nnz_cap = n_edges + 4 * n_nodes;   // padded (x4) CSR upper bound

    // workspace carve-up
    char* ws = (char*)d_ws;
    size_t off = 0;
    auto carve = [&](size_t bytes) { void* p = ws + off; off += (bytes + 255) & ~(size_t)255; return p; };
    _Float16* Hbuf = (_Float16*)carve((size_t)n_nodes * HID * sizeof(_Float16));
    _Float16* Bbuf = (_Float16*)carve((size_t)n_nodes * HID * sizeof(_Float16));
    _Float16* Bt1  = (_Float16*)carve((size_t)IN_DIM * HID * sizeof(_Float16));
    _Float16* Bt2  = (_Float16*)carve((size_t)HID * HID * sizeof(_Float16));
    _Float16* Bt3  = (_Float16*)carve((size_t)HID * OUT * sizeof(_Float16));
    int*   deg     = (int*)carve((size_t)n_nodes * DSTR * sizeof(int));  // line-padded
    float* dinv    = (float*)carve((size_t)n_nodes * sizeof(float));
    int*   row_ptr = (int*)carve((size_t)(n_nodes + 1) * sizeof(int));
    int*   pos     = (int*)carve((size_t)n_edges * sizeof(int));
    int*   partial = (int*)carve(256 * sizeof(int));
    unsigned* csr  = (unsigned*)carve((size_t)nnz_cap * sizeof(unsigned));
    if (off > ws_size) return;

    float* out = (float*)d_out;

    // ---- fused preprocessing (cooperative: 7 dispatches -> 1) ----
    {
        void* kargs[] = {
            (void*)&ei, (void*)&n_edges, (void*)&n_nodes,
            (void*)&deg, (void*)&pos, (void*)&row_ptr, (void*)&partial,
            (void*)&dinv, (void*)&csr,
            (void*)&W1, (void*)&W2, (void*)&W3,
            (void*)&Bt1, (void*)&Bt2, (void*)&Bt3,
        };
        hipLaunchCooperativeKernel((const void*)preproc_kernel,
                                   dim3(1024), dim3(256), kargs, 0, stream);
    }

    int spmm_grid = (n_nodes + 3) / 4;
    int gemm_grid = (n_nodes + 127) / 128;

    // ---- layer 1 ----
    mfma_gemm_kernel<float, 256, 128><<<gemm_grid, 256, 0, stream>>>(x, Bt1, Hbuf, n_nodes);
    spmm_kernel<128, _Float16><<<spmm_grid, 256, 0, stream>>>(Hbuf, row_ptr, csr, b1, Bbuf, n_nodes);
    // ---- layer 2 ----
    mfma_gemm_kernel<_Float16, 128, 128><<<gemm_grid, 256, 0, stream>>>(Bbuf, Bt2, Hbuf, n_nodes);
    spmm_kernel<128, _Float16><<<spmm_grid, 256, 0, stream>>>(Hbuf, row_ptr, csr, b2, Bbuf, n_nodes);
    // ---- layer 3 ----
    mfma_gemm_kernel<_Float16, 128, 64><<<gemm_grid, 256, 0, stream>>>(Bbuf, Bt3, Hbuf, n_nodes);
    spmm_kernel<64, float><<<spmm_grid, 256, 0, stream>>>(Hbuf, row_ptr, csr, b3, out, n_nodes);
}

// Round 12
// 189.330 us; speedup vs baseline: 3.6573x; 3.6573x over previous
//
#include <hip/hip_runtime.h>
#include <math.h>

typedef _Float16 half8v __attribute__((ext_vector_type(8)));
typedef float    f32x4  __attribute__((ext_vector_type(4)));

#define DSTR 16   // degree-counter stride (ints): 1 counter per 64B line

// ---------------------------------------------------------------------------
// GCN 3-layer forward:  h = relu(Ahat @ (x @ W) + b)  x3
// Ahat = D^-1/2 (A + I) D^-1/2, CSR-by-dst, rows padded to x4, entries packed
// u32 {col:16 | w_fp16:16}. Separate small stream-ordered preproc kernels
// (R11 showed cooperative grid.sync costs ~100us/sync here - never again).
// GEMMs on mfma_f32_16x16x32_f16 with B in LDS; H fp16; half8 gathers.
// ---------------------------------------------------------------------------

// fused: zero deg counters + weight convert/transpose (wtot >= n covers both)
// W1:[256,128] W2:[128,128] W3:[128,64]
__global__ void wcvt_zero_kernel(const float* __restrict__ W1, _Float16* __restrict__ Bt1,
                                 const float* __restrict__ W2, _Float16* __restrict__ Bt2,
                                 const float* __restrict__ W3, _Float16* __restrict__ Bt3,
                                 int* __restrict__ deg, int n) {
    int i = blockIdx.x * blockDim.x + threadIdx.x;
    if (i < n) deg[(size_t)i * DSTR] = 0;
    if (i < 256 * 128) {
        int k = i & 255, nn = i >> 8;
        Bt1[i] = (_Float16)W1[(size_t)k * 128 + nn];
    } else if (i < 256 * 128 + 128 * 128) {
        int j = i - 256 * 128;
        int k = j & 127, nn = j >> 7;
        Bt2[j] = (_Float16)W2[(size_t)k * 128 + nn];
    } else if (i < 256 * 128 + 128 * 128 + 128 * 64) {
        int j = i - 256 * 128 - 128 * 128;
        int k = j & 127, nn = j >> 7;
        Bt3[j] = (_Float16)W3[(size_t)k * 64 + nn];
    }
}

// deg + slot position in one atomic pass; counters padded to 64B lines
__global__ void deg_pos_kernel(const int* __restrict__ dst, int* __restrict__ deg,
                               int* __restrict__ pos, int E) {
    int i = blockIdx.x * blockDim.x + threadIdx.x;
    if (i < E) pos[i] = atomicAdd(&deg[(size_t)dst[i] * DSTR], 1);
}

// --- scan over padded row sizes pad(i)=((deg+1)->x4); also emits dinv ------
__global__ __launch_bounds__(256) void scan1_kernel(const int* __restrict__ deg,
                                                    int* __restrict__ row_ptr,
                                                    int* __restrict__ partial,
                                                    float* __restrict__ dinv, int n) {
    __shared__ int s[256];
    int tid = threadIdx.x;
    int i = blockIdx.x * 256 + tid;
    int dg = (i < n) ? deg[(size_t)i * DSTR] : 0;
    if (i < n) dinv[i] = 1.0f / sqrtf((float)(dg + 1));   // +1 self-loop
    int v = (i < n) ? ((dg + 4) & ~3) : 0;                // (deg+1) -> mult of 4
    s[tid] = v;
    __syncthreads();
    #pragma unroll
    for (int off = 1; off < 256; off <<= 1) {
        int t = (tid >= off) ? s[tid - off] : 0;
        __syncthreads();
        s[tid] += t;
        __syncthreads();
    }
    if (i < n) row_ptr[i + 1] = s[tid];
    if (tid == 255) partial[blockIdx.x] = s[255];
}

__global__ __launch_bounds__(256) void scan2_kernel(int* __restrict__ partial, int nb) {
    __shared__ int s[256];
    int tid = threadIdx.x;
    int v = (tid < nb) ? partial[tid] : 0;
    s[tid] = v;
    __syncthreads();
    #pragma unroll
    for (int off = 1; off < 256; off <<= 1) {
        int t = (tid >= off) ? s[tid - off] : 0;
        __syncthreads();
        s[tid] += t;
        __syncthreads();
    }
    if (tid < nb) partial[tid] = s[tid] - v;     // exclusive
}

__global__ void scan3_kernel(const int* __restrict__ partial, int* __restrict__ row_ptr, int n) {
    int i = blockIdx.x * blockDim.x + threadIdx.x;
    if (i == 0) row_ptr[0] = 0;
    if (i < n) row_ptr[i + 1] += partial[i >> 8];
}

// atomic-free fill: edges + self-loops + explicit pad-slot zeroing.
// entry = col:u16 | w:fp16<<16
__global__ void fill_kernel(const int* __restrict__ ei, const int* __restrict__ pos,
                            const int* __restrict__ deg, const float* __restrict__ dinv,
                            const int* __restrict__ row_ptr, unsigned* __restrict__ csr,
                            int E, int n) {
    int idx = blockIdx.x * blockDim.x + threadIdx.x;
    int s, d, slot;
    if (idx < E)          { s = ei[idx]; d = ei[E + idx]; slot = pos[idx]; }
    else if (idx < E + n) { s = d = idx - E; slot = deg[(size_t)d * DSTR]; }
    else if (idx < E + n + 3 * n) {
        int p = idx - E - n;
        int dd = p / 3, pi = p - dd * 3;
        int dg = deg[(size_t)dd * DSTR];
        int real = dg + 1;
        int padded = (dg + 4) & ~3;
        if (pi < padded - real) csr[row_ptr[dd] + real + pi] = 0u;
        return;
    } else return;
    float w = dinv[s] * dinv[d];
    union { _Float16 h; unsigned short u; } cv; cv.h = (_Float16)w;
    csr[row_ptr[d] + slot] = (unsigned)s | ((unsigned)cv.u << 16);
}

// ---------------------------------------------------------------------------
// MFMA GEMM: C[M,TNv](fp16) = A[M,K] @ Bt[TNv,K]^T.  K,TNv compile-time.
// 256 threads = 4 waves x 32 rows = 128 rows/block.
// B staged ONCE into LDS (padded stride KP=K+8 halves -> 2-way banks, free).
// Fragments (16x16x32 f16):
//   A reg j: A[row=lane&15][k=(lane>>4)*8+j]
//   B reg j: B[k=(lane>>4)*8+j][col=lane&15]   from Bt[col][k]
//   D reg j: D[row=(lane>>4)*4+j][col=lane&15] (m89/m91-verified)
// ---------------------------------------------------------------------------
template <typename TA, int K, int TNv>
__global__ __launch_bounds__(256) void mfma_gemm_kernel(const TA* __restrict__ A,
                                                        const _Float16* __restrict__ Bt,
                                                        _Float16* __restrict__ C,
                                                        int M) {
    constexpr int NF = TNv / 16;
    constexpr int KP = K + 8;                      // padded row stride (halves)
    constexpr int CHUNKS = (TNv * (K / 8)) / 256;  // 16B chunks per thread
    __shared__ _Float16 Bs[TNv * KP];

    int tid = threadIdx.x;
    #pragma unroll
    for (int i = 0; i < CHUNKS; ++i) {
        int id = tid + i * 256;
        int n  = id / (K / 8);
        int k8 = (id % (K / 8)) * 8;
        *(half8v*)(&Bs[n * KP + k8]) = *(const half8v*)(Bt + (size_t)n * K + k8);
    }
    __syncthreads();

    int lane = tid & 63;
    int wave = tid >> 6;
    int r  = lane & 15;
    int kg = lane >> 4;
    int row0 = blockIdx.x * 128 + wave * 32;

    f32x4 acc[2][NF];
    #pragma unroll
    for (int mf = 0; mf < 2; ++mf)
        #pragma unroll
        for (int nf = 0; nf < NF; ++nf)
            acc[mf][nf] = (f32x4){0.f, 0.f, 0.f, 0.f};

    int rowA0 = row0 + r;      if (rowA0 > M - 1) rowA0 = M - 1;
    int rowA1 = row0 + 16 + r; if (rowA1 > M - 1) rowA1 = M - 1;
    const TA* pa0 = A + (size_t)rowA0 * K + kg * 8;
    const TA* pa1 = A + (size_t)rowA1 * K + kg * 8;

    #pragma unroll
    for (int kc = 0; kc < K; kc += 32) {
        half8v a0, a1;
        if constexpr (__is_same(TA, float)) {
            float4 l0 = *(const float4*)(pa0 + kc);
            float4 h0 = *(const float4*)(pa0 + kc + 4);
            float4 l1 = *(const float4*)(pa1 + kc);
            float4 h1 = *(const float4*)(pa1 + kc + 4);
            a0[0] = (_Float16)l0.x; a0[1] = (_Float16)l0.y; a0[2] = (_Float16)l0.z; a0[3] = (_Float16)l0.w;
            a0[4] = (_Float16)h0.x; a0[5] = (_Float16)h0.y; a0[6] = (_Float16)h0.z; a0[7] = (_Float16)h0.w;
            a1[0] = (_Float16)l1.x; a1[1] = (_Float16)l1.y; a1[2] = (_Float16)l1.z; a1[3] = (_Float16)l1.w;
            a1[4] = (_Float16)h1.x; a1[5] = (_Float16)h1.y; a1[6] = (_Float16)h1.z; a1[7] = (_Float16)h1.w;
        } else {
            a0 = *(const half8v*)(pa0 + kc);
            a1 = *(const half8v*)(pa1 + kc);
        }
        #pragma unroll
        for (int nf = 0; nf < NF; ++nf) {
            half8v b = *(const half8v*)(&Bs[(nf * 16 + r) * KP + kc + kg * 8]);
            acc[0][nf] = __builtin_amdgcn_mfma_f32_16x16x32_f16(a0, b, acc[0][nf], 0, 0, 0);
            acc[1][nf] = __builtin_amdgcn_mfma_f32_16x16x32_f16(a1, b, acc[1][nf], 0, 0, 0);
        }
    }

    #pragma unroll
    for (int mf = 0; mf < 2; ++mf) {
        #pragma unroll
        for (int j = 0; j < 4; ++j) {
            int row = row0 + mf * 16 + kg * 4 + j;
            if (row < M) {
                #pragma unroll
                for (int nf = 0; nf < NF; ++nf)
                    C[(size_t)row * TNv + nf * 16 + r] = (_Float16)acc[mf][nf][j];
            }
        }
    }
}

// ---------------------------------------------------------------------------
// SpMM + bias + relu, fp16 H, rows padded to x4, packed u32 CSR.
// One wave per node; half8 (16B) gathers, row split over LPR lanes.
// Batches: 16 edges (U16 in flight) / 8 / 4 tails.
// ---------------------------------------------------------------------------
template <int F, typename TOut>
__global__ __launch_bounds__(256) void spmm_kernel(const _Float16* __restrict__ H,
                                                   const int* __restrict__ row_ptr,
                                                   const unsigned* __restrict__ csr,
                                                   const float* __restrict__ bias,
                                                   TOut* __restrict__ out,
                                                   int n_nodes) {
    constexpr int LPR = F / 8;       // lanes per row: 16 (F=128) / 8 (F=64)
    constexpr int RPW = 64 / LPR;    // rows per gather instr: 4 / 8
    constexpr int U16 = 16 / RPW;    // in flight, 16-edge batch: 4 / 2
    constexpr int U8  = 8 / RPW;     // in flight, 8-edge batch: 2 / 1
    int wave = threadIdx.x >> 6;
    int lane = threadIdx.x & 63;
    int node = (blockIdx.x << 2) + wave;
    if (node >= n_nodes) return;

    int h  = lane / LPR;             // edge slot group (0..RPW-1)
    int fi = (lane % LPR) * 8;       // feature offset (halves)
    const _Float16* Hf = H + fi;

    int e0 = row_ptr[node];
    int e1 = row_ptr[node + 1];

    float acc[U16][8];
    #pragma unroll
    for (int i = 0; i < U16; ++i)
        #pragma unroll
        for (int j = 0; j < 8; ++j) acc[i][j] = 0.f;

    auto unpack_w = [](unsigned pk) -> float {
        union { unsigned short u; _Float16 h; } cv;
        cv.u = (unsigned short)(pk >> 16);
        return (float)cv.h;
    };

    int e = e0;
    for (; e + 16 <= e1; e += 16) {
        unsigned pk[U16];
        #pragma unroll
        for (int i = 0; i < U16; ++i) pk[i] = csr[e + i * RPW + h];
        #pragma unroll
        for (int i = 0; i < U16; ++i) {
            half8v v = *(const half8v*)(Hf + (size_t)(pk[i] & 0xFFFFu) * F);
            float w = unpack_w(pk[i]);
            #pragma unroll
            for (int j = 0; j < 8; ++j) acc[i][j] = fmaf(w, (float)v[j], acc[i][j]);
        }
    }
    if (e + 8 <= e1) {
        unsigned pk[U8];
        #pragma unroll
        for (int i = 0; i < U8; ++i) pk[i] = csr[e + i * RPW + h];
        #pragma unroll
        for (int i = 0; i < U8; ++i) {
            half8v v = *(const half8v*)(Hf + (size_t)(pk[i] & 0xFFFFu) * F);
            float w = unpack_w(pk[i]);
            #pragma unroll
            for (int j = 0; j < 8; ++j) acc[i][j] = fmaf(w, (float)v[j], acc[i][j]);
        }
        e += 8;
    }
    if (e < e1) {   // exactly 4 remaining (rows padded to x4)
        unsigned pk = (RPW == 4 || h < 4) ? csr[e + h] : 0u;
        half8v v = *(const half8v*)(Hf + (size_t)(pk & 0xFFFFu) * F);
        float w = unpack_w(pk);
        #pragma unroll
        for (int j = 0; j < 8; ++j) acc[0][j] = fmaf(w, (float)v[j], acc[0][j]);
    }

    float t[8];
    #pragma unroll
    for (int j = 0; j < 8; ++j) {
        t[j] = acc[0][j];
        #pragma unroll
        for (int i = 1; i < U16; ++i) t[j] += acc[i][j];
    }
    #pragma unroll
    for (int off = LPR; off < 64; off <<= 1)
        #pragma unroll
        for (int j = 0; j < 8; ++j) t[j] += __shfl_xor(t[j], off);

    if (h == 0) {
        float4 bl = *(const float4*)(bias + fi);
        float4 bh = *(const float4*)(bias + fi + 4);
        float o[8];
        o[0] = fmaxf(t[0] + bl.x, 0.f); o[1] = fmaxf(t[1] + bl.y, 0.f);
        o[2] = fmaxf(t[2] + bl.z, 0.f); o[3] = fmaxf(t[3] + bl.w, 0.f);
        o[4] = fmaxf(t[4] + bh.x, 0.f); o[5] = fmaxf(t[5] + bh.y, 0.f);
        o[6] = fmaxf(t[6] + bh.z, 0.f); o[7] = fmaxf(t[7] + bh.w, 0.f);
        if constexpr (__is_same(TOut, _Float16)) {
            half8v hv;
            #pragma unroll
            for (int j = 0; j < 8; ++j) hv[j] = (_Float16)o[j];
            *(half8v*)(out + (size_t)node * F + fi) = hv;
        } else {
            *(float4*)(out + (size_t)node * F + fi)     = make_float4(o[0], o[1], o[2], o[3]);
            *(float4*)(out + (size_t)node * F + fi + 4) = make_float4(o[4], o[5], o[6], o[7]);
        }
    }
}

// ---------------------------------------------------------------------------

extern "C" void kernel_launch(void* const* d_in, const int* in_sizes, int n_in,
                              void* d_out, int out_size, void* d_ws, size_t ws_size,
                              hipStream_t stream) {
    const float* x  = (const float*)d_in[0];
    const int*   ei = (const int*)d_in[1];     // [2, E] int32
    const float* W1 = (const float*)d_in[2];
    const float* b1 = (const float*)d_in[3];
    const float* W2 = (const float*)d_in[4];
    const float* b2 = (const float*)d_in[5];
    const float* W3 = (const float*)d_in[6];
    const float* b3 = (const float*)d_in[7];

    const int IN_DIM = 256, HID = 128, OUT = 64;
    int n_nodes = in_sizes[0] / IN_DIM;    // 50000 (< 65536 required for u32 pack)
    int n_edges = in_sizes[1] / 2;         // 800000
    int nnz_cap = n_edges + 4 * n_nodes;   // padded (x4) CSR upper bound

    // workspace carve-up
    char* ws = (char*)d_ws;
    size_t off = 0;
    auto carve = [&](size_t bytes) { void* p = ws + off; off += (bytes + 255) & ~(size_t)255; return p; };
    _Float16* Hbuf = (_Float16*)carve((size_t)n_nodes * HID * sizeof(_Float16));
    _Float16* Bbuf = (_Float16*)carve((size_t)n_nodes * HID * sizeof(_Float16));
    _Float16* Bt1  = (_Float16*)carve((size_t)IN_DIM * HID * sizeof(_Float16));
    _Float16* Bt2  = (_Float16*)carve((size_t)HID * HID * sizeof(_Float16));
    _Float16* Bt3  = (_Float16*)carve((size_t)HID * OUT * sizeof(_Float16));
    int*   deg     = (int*)carve((size_t)n_nodes * DSTR * sizeof(int));  // line-padded
    float* dinv    = (float*)carve((size_t)n_nodes * sizeof(float));
    int*   row_ptr = (int*)carve((size_t)(n_nodes + 1) * sizeof(int));
    int*   pos     = (int*)carve((size_t)n_edges * sizeof(int));
    int*   partial = (int*)carve(256 * sizeof(int));
    unsigned* csr  = (unsigned*)carve((size_t)nnz_cap * sizeof(unsigned));
    if (off > ws_size) return;

    float* out = (float*)d_out;

    const int B = 256;
    int nb = (n_nodes + 255) / 256;
    int wtot = IN_DIM * HID + HID * HID + HID * OUT;   // 57344 >= n_nodes

    // ---- graph preprocessing (stream-ordered small kernels) ----
    wcvt_zero_kernel<<<(wtot + B - 1) / B, B, 0, stream>>>(W1, Bt1, W2, Bt2, W3, Bt3,
                                                           deg, n_nodes);
    deg_pos_kernel<<<(n_edges + B - 1) / B, B, 0, stream>>>(ei + n_edges, deg, pos, n_edges);
    scan1_kernel<<<nb, 256, 0, stream>>>(deg, row_ptr, partial, dinv, n_nodes);
    scan2_kernel<<<1, 256, 0, stream>>>(partial, nb);
    scan3_kernel<<<(n_nodes + B - 1) / B, B, 0, stream>>>(partial, row_ptr, n_nodes);
    fill_kernel<<<(n_edges + 4 * n_nodes + B - 1) / B, B, 0, stream>>>(ei, pos, deg, dinv,
                                                                       row_ptr, csr, n_edges, n_nodes);

    int spmm_grid = (n_nodes + 3) / 4;
    int gemm_grid = (n_nodes + 127) / 128;

    // ---- layer 1 ----
    mfma_gemm_kernel<float, 256, 128><<<gemm_grid, 256, 0, stream>>>(x, Bt1, Hbuf, n_nodes);
    spmm_kernel<128, _Float16><<<spmm_grid, 256, 0, stream>>>(Hbuf, row_ptr, csr, b1, Bbuf, n_nodes);
    // ---- layer 2 ----
    mfma_gemm_kernel<_Float16, 128, 128><<<gemm_grid, 256, 0, stream>>>(Bbuf, Bt2, Hbuf, n_nodes);
    spmm_kernel<128, _Float16><<<spmm_grid, 256, 0, stream>>>(Hbuf, row_ptr, csr, b2, Bbuf, n_nodes);
    // ---- layer 3 ----
    mfma_gemm_kernel<_Float16, 128, 64><<<gemm_grid, 256, 0, stream>>>(Bbuf, Bt3, Hbuf, n_nodes);
    spmm_kernel<64, float><<<spmm_grid, 256, 0, stream>>>(Hbuf, row_ptr, csr, b3, out, n_nodes);
}

// Round 13
// 189.114 us; speedup vs baseline: 3.6615x; 1.0011x over previous
//
#include <hip/hip_runtime.h>
#include <math.h>

typedef _Float16 half8v __attribute__((ext_vector_type(8)));
typedef float    f32x4  __attribute__((ext_vector_type(4)));

#define DSTR 16   // degree-counter stride (ints): 1 counter per 64B line

// ---------------------------------------------------------------------------
// GCN 3-layer forward:  h = relu(Ahat @ (x @ W) + b)  x3
// Ahat = D^-1/2 (A + I) D^-1/2, CSR-by-dst, rows padded to x4, entries packed
// u32 {col:16 | w_fp16:16}. Separate small stream-ordered preproc kernels
// (R11 showed cooperative grid.sync costs ~100us/sync here - never again).
// GEMMs on mfma_f32_16x16x32_f16 with B in LDS; H fp16; half8 gathers.
// ---------------------------------------------------------------------------

// fused: zero deg counters + weight convert/transpose (wtot >= n covers both)
// W1:[256,128] W2:[128,128] W3:[128,64]
__global__ void wcvt_zero_kernel(const float* __restrict__ W1, _Float16* __restrict__ Bt1,
                                 const float* __restrict__ W2, _Float16* __restrict__ Bt2,
                                 const float* __restrict__ W3, _Float16* __restrict__ Bt3,
                                 int* __restrict__ deg, int n) {
    int i = blockIdx.x * blockDim.x + threadIdx.x;
    if (i < n) deg[(size_t)i * DSTR] = 0;
    if (i < 256 * 128) {
        int k = i & 255, nn = i >> 8;
        Bt1[i] = (_Float16)W1[(size_t)k * 128 + nn];
    } else if (i < 256 * 128 + 128 * 128) {
        int j = i - 256 * 128;
        int k = j & 127, nn = j >> 7;
        Bt2[j] = (_Float16)W2[(size_t)k * 128 + nn];
    } else if (i < 256 * 128 + 128 * 128 + 128 * 64) {
        int j = i - 256 * 128 - 128 * 128;
        int k = j & 127, nn = j >> 7;
        Bt3[j] = (_Float16)W3[(size_t)k * 64 + nn];
    }
}

// deg + slot position in one atomic pass; counters padded to 64B lines
__global__ void deg_pos_kernel(const int* __restrict__ dst, int* __restrict__ deg,
                               int* __restrict__ pos, int E) {
    int i = blockIdx.x * blockDim.x + threadIdx.x;
    if (i < E) pos[i] = atomicAdd(&deg[(size_t)dst[i] * DSTR], 1);
}

// --- scan over padded row sizes pad(i)=((deg+1)->x4); also emits dinv ------
__global__ __launch_bounds__(256) void scan1_kernel(const int* __restrict__ deg,
                                                    int* __restrict__ row_ptr,
                                                    int* __restrict__ partial,
                                                    float* __restrict__ dinv, int n) {
    __shared__ int s[256];
    int tid = threadIdx.x;
    int i = blockIdx.x * 256 + tid;
    int dg = (i < n) ? deg[(size_t)i * DSTR] : 0;
    if (i < n) dinv[i] = 1.0f / sqrtf((float)(dg + 1));   // +1 self-loop
    int v = (i < n) ? ((dg + 4) & ~3) : 0;                // (deg+1) -> mult of 4
    s[tid] = v;
    __syncthreads();
    #pragma unroll
    for (int off = 1; off < 256; off <<= 1) {
        int t = (tid >= off) ? s[tid - off] : 0;
        __syncthreads();
        s[tid] += t;
        __syncthreads();
    }
    if (i < n) row_ptr[i + 1] = s[tid];
    if (tid == 255) partial[blockIdx.x] = s[255];
}

__global__ __launch_bounds__(256) void scan2_kernel(int* __restrict__ partial, int nb) {
    __shared__ int s[256];
    int tid = threadIdx.x;
    int v = (tid < nb) ? partial[tid] : 0;
    s[tid] = v;
    __syncthreads();
    #pragma unroll
    for (int off = 1; off < 256; off <<= 1) {
        int t = (tid >= off) ? s[tid - off] : 0;
        __syncthreads();
        s[tid] += t;
        __syncthreads();
    }
    if (tid < nb) partial[tid] = s[tid] - v;     // exclusive
}

__global__ void scan3_kernel(const int* __restrict__ partial, int* __restrict__ row_ptr, int n) {
    int i = blockIdx.x * blockDim.x + threadIdx.x;
    if (i == 0) row_ptr[0] = 0;
    if (i < n) row_ptr[i + 1] += partial[i >> 8];
}

// atomic-free fill: edges + self-loops + explicit pad-slot zeroing.
// entry = col:u16 | w:fp16<<16
__global__ void fill_kernel(const int* __restrict__ ei, const int* __restrict__ pos,
                            const int* __restrict__ deg, const float* __restrict__ dinv,
                            const int* __restrict__ row_ptr, unsigned* __restrict__ csr,
                            int E, int n) {
    int idx = blockIdx.x * blockDim.x + threadIdx.x;
    int s, d, slot;
    if (idx < E)          { s = ei[idx]; d = ei[E + idx]; slot = pos[idx]; }
    else if (idx < E + n) { s = d = idx - E; slot = deg[(size_t)d * DSTR]; }
    else if (idx < E + n + 3 * n) {
        int p = idx - E - n;
        int dd = p / 3, pi = p - dd * 3;
        int dg = deg[(size_t)dd * DSTR];
        int real = dg + 1;
        int padded = (dg + 4) & ~3;
        if (pi < padded - real) csr[row_ptr[dd] + real + pi] = 0u;
        return;
    } else return;
    float w = dinv[s] * dinv[d];
    union { _Float16 h; unsigned short u; } cv; cv.h = (_Float16)w;
    csr[row_ptr[d] + slot] = (unsigned)s | ((unsigned)cv.u << 16);
}

// ---------------------------------------------------------------------------
// MFMA GEMM: C[M,TNv](fp16) = A[M,K] @ Bt[TNv,K]^T.  K,TNv compile-time.
// 256 threads = 4 waves x 32 rows = 128 rows/block.
// B staged ONCE into LDS (padded stride KP=K+8 halves -> 2-way banks, free).
// Fragments (16x16x32 f16):
//   A reg j: A[row=lane&15][k=(lane>>4)*8+j]
//   B reg j: B[k=(lane>>4)*8+j][col=lane&15]   from Bt[col][k]
//   D reg j: D[row=(lane>>4)*4+j][col=lane&15] (m89/m91-verified)
// ---------------------------------------------------------------------------
template <typename TA, int K, int TNv>
__global__ __launch_bounds__(256) void mfma_gemm_kernel(const TA* __restrict__ A,
                                                        const _Float16* __restrict__ Bt,
                                                        _Float16* __restrict__ C,
                                                        int M) {
    constexpr int NF = TNv / 16;
    constexpr int KP = K + 8;                      // padded row stride (halves)
    constexpr int CHUNKS = (TNv * (K / 8)) / 256;  // 16B chunks per thread
    __shared__ _Float16 Bs[TNv * KP];

    int tid = threadIdx.x;
    #pragma unroll
    for (int i = 0; i < CHUNKS; ++i) {
        int id = tid + i * 256;
        int n  = id / (K / 8);
        int k8 = (id % (K / 8)) * 8;
        *(half8v*)(&Bs[n * KP + k8]) = *(const half8v*)(Bt + (size_t)n * K + k8);
    }
    __syncthreads();

    int lane = tid & 63;
    int wave = tid >> 6;
    int r  = lane & 15;
    int kg = lane >> 4;
    int row0 = blockIdx.x * 128 + wave * 32;

    f32x4 acc[2][NF];
    #pragma unroll
    for (int mf = 0; mf < 2; ++mf)
        #pragma unroll
        for (int nf = 0; nf < NF; ++nf)
            acc[mf][nf] = (f32x4){0.f, 0.f, 0.f, 0.f};

    int rowA0 = row0 + r;      if (rowA0 > M - 1) rowA0 = M - 1;
    int rowA1 = row0 + 16 + r; if (rowA1 > M - 1) rowA1 = M - 1;
    const TA* pa0 = A + (size_t)rowA0 * K + kg * 8;
    const TA* pa1 = A + (size_t)rowA1 * K + kg * 8;

    #pragma unroll
    for (int kc = 0; kc < K; kc += 32) {
        half8v a0, a1;
        if constexpr (__is_same(TA, float)) {
            float4 l0 = *(const float4*)(pa0 + kc);
            float4 h0 = *(const float4*)(pa0 + kc + 4);
            float4 l1 = *(const float4*)(pa1 + kc);
            float4 h1 = *(const float4*)(pa1 + kc + 4);
            a0[0] = (_Float16)l0.x; a0[1] = (_Float16)l0.y; a0[2] = (_Float16)l0.z; a0[3] = (_Float16)l0.w;
            a0[4] = (_Float16)h0.x; a0[5] = (_Float16)h0.y; a0[6] = (_Float16)h0.z; a0[7] = (_Float16)h0.w;
            a1[0] = (_Float16)l1.x; a1[1] = (_Float16)l1.y; a1[2] = (_Float16)l1.z; a1[3] = (_Float16)l1.w;
            a1[4] = (_Float16)h1.x; a1[5] = (_Float16)h1.y; a1[6] = (_Float16)h1.z; a1[7] = (_Float16)h1.w;
        } else {
            a0 = *(const half8v*)(pa0 + kc);
            a1 = *(const half8v*)(pa1 + kc);
        }
        #pragma unroll
        for (int nf = 0; nf < NF; ++nf) {
            half8v b = *(const half8v*)(&Bs[(nf * 16 + r) * KP + kc + kg * 8]);
            acc[0][nf] = __builtin_amdgcn_mfma_f32_16x16x32_f16(a0, b, acc[0][nf], 0, 0, 0);
            acc[1][nf] = __builtin_amdgcn_mfma_f32_16x16x32_f16(a1, b, acc[1][nf], 0, 0, 0);
        }
    }

    #pragma unroll
    for (int mf = 0; mf < 2; ++mf) {
        #pragma unroll
        for (int j = 0; j < 4; ++j) {
            int row = row0 + mf * 16 + kg * 4 + j;
            if (row < M) {
                #pragma unroll
                for (int nf = 0; nf < NF; ++nf)
                    C[(size_t)row * TNv + nf * 16 + r] = (_Float16)acc[mf][nf][j];
            }
        }
    }
}

// ---------------------------------------------------------------------------
// SpMM + bias + relu, fp16 H, rows padded to x4, packed u32 CSR.
// One wave per node; half8 (16B) gathers, row split over LPR lanes.
// Batches: 16 edges (U16 in flight) / 8 / 4 tails.
// ---------------------------------------------------------------------------
template <int F, typename TOut>
__global__ __launch_bounds__(256) void spmm_kernel(const _Float16* __restrict__ H,
                                                   const int* __restrict__ row_ptr,
                                                   const unsigned* __restrict__ csr,
                                                   const float* __restrict__ bias,
                                                   TOut* __restrict__ out,
                                                   int n_nodes) {
    constexpr int LPR = F / 8;       // lanes per row: 16 (F=128) / 8 (F=64)
    constexpr int RPW = 64 / LPR;    // rows per gather instr: 4 / 8
    constexpr int U16 = 16 / RPW;    // in flight, 16-edge batch: 4 / 2
    constexpr int U8  = 8 / RPW;     // in flight, 8-edge batch: 2 / 1
    int wave = threadIdx.x >> 6;
    int lane = threadIdx.x & 63;
    int node = (blockIdx.x << 2) + wave;
    if (node >= n_nodes) return;

    int h  = lane / LPR;             // edge slot group (0..RPW-1)
    int fi = (lane % LPR) * 8;       // feature offset (halves)
    const _Float16* Hf = H + fi;

    int e0 = row_ptr[node];
    int e1 = row_ptr[node + 1];

    float acc[U16][8];
    #pragma unroll
    for (int i = 0; i < U16; ++i)
        #pragma unroll
        for (int j = 0; j < 8; ++j) acc[i][j] = 0.f;

    auto unpack_w = [](unsigned pk) -> float {
        union { unsigned short u; _Float16 h; } cv;
        cv.u = (unsigned short)(pk >> 16);
        return (float)cv.h;
    };

    int e = e0;
    for (; e + 16 <= e1; e += 16) {
        unsigned pk[U16];
        #pragma unroll
        for (int i = 0; i < U16; ++i) pk[i] = csr[e + i * RPW + h];
        #pragma unroll
        for (int i = 0; i < U16; ++i) {
            half8v v = *(const half8v*)(Hf + (size_t)(pk[i] & 0xFFFFu) * F);
            float w = unpack_w(pk[i]);
            #pragma unroll
            for (int j = 0; j < 8; ++j) acc[i][j] = fmaf(w, (float)v[j], acc[i][j]);
        }
    }
    if (e + 8 <= e1) {
        unsigned pk[U8];
        #pragma unroll
        for (int i = 0; i < U8; ++i) pk[i] = csr[e + i * RPW + h];
        #pragma unroll
        for (int i = 0; i < U8; ++i) {
            half8v v = *(const half8v*)(Hf + (size_t)(pk[i] & 0xFFFFu) * F);
            float w = unpack_w(pk[i]);
            #pragma unroll
            for (int j = 0; j < 8; ++j) acc[i][j] = fmaf(w, (float)v[j], acc[i][j]);
        }
        e += 8;
    }
    if (e < e1) {   // exactly 4 remaining (rows padded to x4)
        unsigned pk = (RPW == 4 || h < 4) ? csr[e + h] : 0u;
        half8v v = *(const half8v*)(Hf + (size_t)(pk & 0xFFFFu) * F);
        float w = unpack_w(pk);
        #pragma unroll
        for (int j = 0; j < 8; ++j) acc[0][j] = fmaf(w, (float)v[j], acc[0][j]);
    }

    float t[8];
    #pragma unroll
    for (int j = 0; j < 8; ++j) {
        t[j] = acc[0][j];
        #pragma unroll
        for (int i = 1; i < U16; ++i) t[j] += acc[i][j];
    }
    #pragma unroll
    for (int off = LPR; off < 64; off <<= 1)
        #pragma unroll
        for (int j = 0; j < 8; ++j) t[j] += __shfl_xor(t[j], off);

    if (h == 0) {
        float4 bl = *(const float4*)(bias + fi);
        float4 bh = *(const float4*)(bias + fi + 4);
        float o[8];
        o[0] = fmaxf(t[0] + bl.x, 0.f); o[1] = fmaxf(t[1] + bl.y, 0.f);
        o[2] = fmaxf(t[2] + bl.z, 0.f); o[3] = fmaxf(t[3] + bl.w, 0.f);
        o[4] = fmaxf(t[4] + bh.x, 0.f); o[5] = fmaxf(t[5] + bh.y, 0.f);
        o[6] = fmaxf(t[6] + bh.z, 0.f); o[7] = fmaxf(t[7] + bh.w, 0.f);
        if constexpr (__is_same(TOut, _Float16)) {
            half8v hv;
            #pragma unroll
            for (int j = 0; j < 8; ++j) hv[j] = (_Float16)o[j];
            *(half8v*)(out + (size_t)node * F + fi) = hv;
        } else {
            *(float4*)(out + (size_t)node * F + fi)     = make_float4(o[0], o[1], o[2], o[3]);
            *(float4*)(out + (size_t)node * F + fi + 4) = make_float4(o[4], o[5], o[6], o[7]);
        }
    }
}

// ---------------------------------------------------------------------------

extern "C" void kernel_launch(void* const* d_in, const int* in_sizes, int n_in,
                              void* d_out, int out_size, void* d_ws, size_t ws_size,
                              hipStream_t stream) {
    const float* x  = (const float*)d_in[0];
    const int*   ei = (const int*)d_in[1];     // [2, E] int32
    const float* W1 = (const float*)d_in[2];
    const float* b1 = (const float*)d_in[3];
    const float* W2 = (const float*)d_in[4];
    const float* b2 = (const float*)d_in[5];
    const float* W3 = (const float*)d_in[6];
    const float* b3 = (const float*)d_in[7];

    const int IN_DIM = 256, HID = 128, OUT = 64;
    int n_nodes = in_sizes[0] / IN_DIM;    // 50000 (< 65536 required for u32 pack)
    int n_edges = in_sizes[1] / 2;         // 800000
    int nnz_cap = n_edges + 4 * n_nodes;   // padded (x4) CSR upper bound

    // workspace carve-up
    char* ws = (char*)d_ws;
    size_t off = 0;
    auto carve = [&](size_t bytes) { void* p = ws + off; off += (bytes + 255) & ~(size_t)255; return p; };
    _Float16* Hbuf = (_Float16*)carve((size_t)n_nodes * HID * sizeof(_Float16));
    _Float16* Bbuf = (_Float16*)carve((size_t)n_nodes * HID * sizeof(_Float16));
    _Float16* Bt1  = (_Float16*)carve((size_t)IN_DIM * HID * sizeof(_Float16));
    _Float16* Bt2  = (_Float16*)carve((size_t)HID * HID * sizeof(_Float16));
    _Float16* Bt3  = (_Float16*)carve((size_t)HID * OUT * sizeof(_Float16));
    int*   deg     = (int*)carve((size_t)n_nodes * DSTR * sizeof(int));  // line-padded
    float* dinv    = (float*)carve((size_t)n_nodes * sizeof(float));
    int*   row_ptr = (int*)carve((size_t)(n_nodes + 1) * sizeof(int));
    int*   pos     = (int*)carve((size_t)n_edges * sizeof(int));
    int*   partial = (int*)carve(256 * sizeof(int));
    unsigned* csr  = (unsigned*)carve((size_t)nnz_cap * sizeof(unsigned));
    if (off > ws_size) return;

    float* out = (float*)d_out;

    const int B = 256;
    int nb = (n_nodes + 255) / 256;
    int wtot = IN_DIM * HID + HID * HID + HID * OUT;   // 57344 >= n_nodes

    // ---- graph preprocessing (stream-ordered small kernels) ----
    wcvt_zero_kernel<<<(wtot + B - 1) / B, B, 0, stream>>>(W1, Bt1, W2, Bt2, W3, Bt3,
                                                           deg, n_nodes);
    deg_pos_kernel<<<(n_edges + B - 1) / B, B, 0, stream>>>(ei + n_edges, deg, pos, n_edges);
    scan1_kernel<<<nb, 256, 0, stream>>>(deg, row_ptr, partial, dinv, n_nodes);
    scan2_kernel<<<1, 256, 0, stream>>>(partial, nb);
    scan3_kernel<<<(n_nodes + B - 1) / B, B, 0, stream>>>(partial, row_ptr, n_nodes);
    fill_kernel<<<(n_edges + 4 * n_nodes + B - 1) / B, B, 0, stream>>>(ei, pos, deg, dinv,
                                                                       row_ptr, csr, n_edges, n_nodes);

    int spmm_grid = (n_nodes + 3) / 4;
    int gemm_grid = (n_nodes + 127) / 128;

    // ---- layer 1 ----
    mfma_gemm_kernel<float, 256, 128><<<gemm_grid, 256, 0, stream>>>(x, Bt1, Hbuf, n_nodes);
    spmm_kernel<128, _Float16><<<spmm_grid, 256, 0, stream>>>(Hbuf, row_ptr, csr, b1, Bbuf, n_nodes);
    // ---- layer 2 ----
    mfma_gemm_kernel<_Float16, 128, 128><<<gemm_grid, 256, 0, stream>>>(Bbuf, Bt2, Hbuf, n_nodes);
    spmm_kernel<128, _Float16><<<spmm_grid, 256, 0, stream>>>(Hbuf, row_ptr, csr, b2, Bbuf, n_nodes);
    // ---- layer 3 ----
    mfma_gemm_kernel<_Float16, 128, 64><<<gemm_grid, 256, 0, stream>>>(Bbuf, Bt3, Hbuf, n_nodes);
    spmm_kernel<64, float><<<spmm_grid, 256, 0, stream>>>(Hbuf, row_ptr, csr, b3, out, n_nodes);
}

// Round 14
// 184.302 us; speedup vs baseline: 3.7571x; 1.0261x over previous
//
#include <hip/hip_runtime.h>
#include <math.h>

typedef _Float16 half8v __attribute__((ext_vector_type(8)));
typedef float    f32x4  __attribute__((ext_vector_type(4)));

#define DSTR 16   // degree-counter stride (ints): 1 counter per 64B line

// ---------------------------------------------------------------------------
// GCN 3-layer forward:  h = relu(Ahat @ (x @ W) + b)  x3
// Ahat = D^-1/2 (A + I) D^-1/2, CSR-by-dst, rows padded to x4, entries packed
// u32 {col:16 | w_fp16:16}. Stream-ordered small preproc kernels (R11: NEVER
// cooperative grid.sync here - ~100us/sync). gemm1 is independent of the CSR
// pipeline -> grid-partition-fused with fill (blocks [0,G) gemm, rest fill)
// to overlap ~13us of GEMM under fill's store traffic.
// GEMMs on mfma_f32_16x16x32_f16 with B in LDS; H fp16; half8 gathers.
// ---------------------------------------------------------------------------

// fused: zero deg counters + weight convert/transpose (wtot >= n covers both)
// W1:[256,128] W2:[128,128] W3:[128,64]
__global__ void wcvt_zero_kernel(const float* __restrict__ W1, _Float16* __restrict__ Bt1,
                                 const float* __restrict__ W2, _Float16* __restrict__ Bt2,
                                 const float* __restrict__ W3, _Float16* __restrict__ Bt3,
                                 int* __restrict__ deg, int n) {
    int i = blockIdx.x * blockDim.x + threadIdx.x;
    if (i < n) deg[(size_t)i * DSTR] = 0;
    if (i < 256 * 128) {
        int k = i & 255, nn = i >> 8;
        Bt1[i] = (_Float16)W1[(size_t)k * 128 + nn];
    } else if (i < 256 * 128 + 128 * 128) {
        int j = i - 256 * 128;
        int k = j & 127, nn = j >> 7;
        Bt2[j] = (_Float16)W2[(size_t)k * 128 + nn];
    } else if (i < 256 * 128 + 128 * 128 + 128 * 64) {
        int j = i - 256 * 128 - 128 * 128;
        int k = j & 127, nn = j >> 7;
        Bt3[j] = (_Float16)W3[(size_t)k * 64 + nn];
    }
}

// deg + slot position in one atomic pass; counters padded to 64B lines
__global__ void deg_pos_kernel(const int* __restrict__ dst, int* __restrict__ deg,
                               int* __restrict__ pos, int E) {
    int i = blockIdx.x * blockDim.x + threadIdx.x;
    if (i < E) pos[i] = atomicAdd(&deg[(size_t)dst[i] * DSTR], 1);
}

// --- scan over padded row sizes pad(i)=((deg+1)->x4); also emits dinv ------
__global__ __launch_bounds__(256) void scan1_kernel(const int* __restrict__ deg,
                                                    int* __restrict__ row_ptr,
                                                    int* __restrict__ partial,
                                                    float* __restrict__ dinv, int n) {
    __shared__ int s[256];
    int tid = threadIdx.x;
    int i = blockIdx.x * 256 + tid;
    int dg = (i < n) ? deg[(size_t)i * DSTR] : 0;
    if (i < n) dinv[i] = 1.0f / sqrtf((float)(dg + 1));   // +1 self-loop
    int v = (i < n) ? ((dg + 4) & ~3) : 0;                // (deg+1) -> mult of 4
    s[tid] = v;
    __syncthreads();
    #pragma unroll
    for (int off = 1; off < 256; off <<= 1) {
        int t = (tid >= off) ? s[tid - off] : 0;
        __syncthreads();
        s[tid] += t;
        __syncthreads();
    }
    if (i < n) row_ptr[i + 1] = s[tid];
    if (tid == 255) partial[blockIdx.x] = s[255];
}

__global__ __launch_bounds__(256) void scan2_kernel(int* __restrict__ partial, int nb) {
    __shared__ int s[256];
    int tid = threadIdx.x;
    int v = (tid < nb) ? partial[tid] : 0;
    s[tid] = v;
    __syncthreads();
    #pragma unroll
    for (int off = 1; off < 256; off <<= 1) {
        int t = (tid >= off) ? s[tid - off] : 0;
        __syncthreads();
        s[tid] += t;
        __syncthreads();
    }
    if (tid < nb) partial[tid] = s[tid] - v;     // exclusive
}

__global__ void scan3_kernel(const int* __restrict__ partial, int* __restrict__ row_ptr, int n) {
    int i = blockIdx.x * blockDim.x + threadIdx.x;
    if (i == 0) row_ptr[0] = 0;
    if (i < n) row_ptr[i + 1] += partial[i >> 8];
}

// ---------------------------------------------------------------------------
// fill body: edges + self-loops + explicit pad-slot zeroing (atomic-free).
// entry = col:u16 | w:fp16<<16
// ---------------------------------------------------------------------------
__device__ __forceinline__ void fill_body(int bid,
                            const int* __restrict__ ei, const int* __restrict__ pos,
                            const int* __restrict__ deg, const float* __restrict__ dinv,
                            const int* __restrict__ row_ptr, unsigned* __restrict__ csr,
                            int E, int n) {
    int idx = bid * 256 + threadIdx.x;
    int s, d, slot;
    if (idx < E)          { s = ei[idx]; d = ei[E + idx]; slot = pos[idx]; }
    else if (idx < E + n) { s = d = idx - E; slot = deg[(size_t)d * DSTR]; }
    else if (idx < E + n + 3 * n) {
        int p = idx - E - n;
        int dd = p / 3, pi = p - dd * 3;
        int dg = deg[(size_t)dd * DSTR];
        int real = dg + 1;
        int padded = (dg + 4) & ~3;
        if (pi < padded - real) csr[row_ptr[dd] + real + pi] = 0u;
        return;
    } else return;
    float w = dinv[s] * dinv[d];
    union { _Float16 h; unsigned short u; } cv; cv.h = (_Float16)w;
    csr[row_ptr[d] + slot] = (unsigned)s | ((unsigned)cv.u << 16);
}

// ---------------------------------------------------------------------------
// MFMA GEMM body: C[M,TNv](fp16) = A[M,K] @ Bt[TNv,K]^T.  K,TNv compile-time.
// 256 threads = 4 waves x 32 rows = 128 rows/block.
// B staged ONCE into LDS (padded stride KP=K+8 halves -> 2-way banks, free).
// Fragments (16x16x32 f16):
//   A reg j: A[row=lane&15][k=(lane>>4)*8+j]
//   B reg j: B[k=(lane>>4)*8+j][col=lane&15]   from Bt[col][k]
//   D reg j: D[row=(lane>>4)*4+j][col=lane&15] (m89/m91-verified)
// ---------------------------------------------------------------------------
template <typename TA, int K, int TNv>
__device__ __forceinline__ void gemm_body(int bid, const TA* __restrict__ A,
                                          const _Float16* __restrict__ Bt,
                                          _Float16* __restrict__ C, int M) {
    constexpr int NF = TNv / 16;
    constexpr int KP = K + 8;                      // padded row stride (halves)
    constexpr int CHUNKS = (TNv * (K / 8)) / 256;  // 16B chunks per thread
    __shared__ _Float16 Bs[TNv * KP];

    int tid = threadIdx.x;
    #pragma unroll
    for (int i = 0; i < CHUNKS; ++i) {
        int id = tid + i * 256;
        int n  = id / (K / 8);
        int k8 = (id % (K / 8)) * 8;
        *(half8v*)(&Bs[n * KP + k8]) = *(const half8v*)(Bt + (size_t)n * K + k8);
    }
    __syncthreads();

    int lane = tid & 63;
    int wave = tid >> 6;
    int r  = lane & 15;
    int kg = lane >> 4;
    int row0 = bid * 128 + wave * 32;

    f32x4 acc[2][NF];
    #pragma unroll
    for (int mf = 0; mf < 2; ++mf)
        #pragma unroll
        for (int nf = 0; nf < NF; ++nf)
            acc[mf][nf] = (f32x4){0.f, 0.f, 0.f, 0.f};

    int rowA0 = row0 + r;      if (rowA0 > M - 1) rowA0 = M - 1;
    int rowA1 = row0 + 16 + r; if (rowA1 > M - 1) rowA1 = M - 1;
    const TA* pa0 = A + (size_t)rowA0 * K + kg * 8;
    const TA* pa1 = A + (size_t)rowA1 * K + kg * 8;

    #pragma unroll
    for (int kc = 0; kc < K; kc += 32) {
        half8v a0, a1;
        if constexpr (__is_same(TA, float)) {
            float4 l0 = *(const float4*)(pa0 + kc);
            float4 h0 = *(const float4*)(pa0 + kc + 4);
            float4 l1 = *(const float4*)(pa1 + kc);
            float4 h1 = *(const float4*)(pa1 + kc + 4);
            a0[0] = (_Float16)l0.x; a0[1] = (_Float16)l0.y; a0[2] = (_Float16)l0.z; a0[3] = (_Float16)l0.w;
            a0[4] = (_Float16)h0.x; a0[5] = (_Float16)h0.y; a0[6] = (_Float16)h0.z; a0[7] = (_Float16)h0.w;
            a1[0] = (_Float16)l1.x; a1[1] = (_Float16)l1.y; a1[2] = (_Float16)l1.z; a1[3] = (_Float16)l1.w;
            a1[4] = (_Float16)h1.x; a1[5] = (_Float16)h1.y; a1[6] = (_Float16)h1.z; a1[7] = (_Float16)h1.w;
        } else {
            a0 = *(const half8v*)(pa0 + kc);
            a1 = *(const half8v*)(pa1 + kc);
        }
        #pragma unroll
        for (int nf = 0; nf < NF; ++nf) {
            half8v b = *(const half8v*)(&Bs[(nf * 16 + r) * KP + kc + kg * 8]);
            acc[0][nf] = __builtin_amdgcn_mfma_f32_16x16x32_f16(a0, b, acc[0][nf], 0, 0, 0);
            acc[1][nf] = __builtin_amdgcn_mfma_f32_16x16x32_f16(a1, b, acc[1][nf], 0, 0, 0);
        }
    }

    #pragma unroll
    for (int mf = 0; mf < 2; ++mf) {
        #pragma unroll
        for (int j = 0; j < 4; ++j) {
            int row = row0 + mf * 16 + kg * 4 + j;
            if (row < M) {
                #pragma unroll
                for (int nf = 0; nf < NF; ++nf)
                    C[(size_t)row * TNv + nf * 16 + r] = (_Float16)acc[mf][nf][j];
            }
        }
    }
}

template <typename TA, int K, int TNv>
__global__ __launch_bounds__(256) void mfma_gemm_kernel(const TA* __restrict__ A,
                                                        const _Float16* __restrict__ Bt,
                                                        _Float16* __restrict__ C,
                                                        int M) {
    gemm_body<TA, K, TNv>(blockIdx.x, A, Bt, C, M);
}

// fused: blocks [0,G) run gemm1 (x @ W1), blocks [G,..) run fill.
// Both inputs ready after scan3; overlaps ~13us of GEMM under fill's stores.
__global__ __launch_bounds__(256) void fill_gemm1_kernel(
    const int* __restrict__ ei, const int* __restrict__ pos,
    const int* __restrict__ deg, const float* __restrict__ dinv,
    const int* __restrict__ row_ptr, unsigned* __restrict__ csr, int E, int n,
    const float* __restrict__ A, const _Float16* __restrict__ Bt,
    _Float16* __restrict__ C, int M, int gemm_blocks)
{
    if (blockIdx.x < gemm_blocks)
        gemm_body<float, 256, 128>(blockIdx.x, A, Bt, C, M);
    else
        fill_body(blockIdx.x - gemm_blocks, ei, pos, deg, dinv, row_ptr, csr, E, n);
}

// ---------------------------------------------------------------------------
// SpMM + bias + relu, fp16 H, rows padded to x4, packed u32 CSR.
// One wave per node; half8 (16B) gathers, row split over LPR lanes.
// Batches: 16 edges (U16 in flight) / 8 / 4 tails.
// ---------------------------------------------------------------------------
template <int F, typename TOut>
__global__ __launch_bounds__(256) void spmm_kernel(const _Float16* __restrict__ H,
                                                   const int* __restrict__ row_ptr,
                                                   const unsigned* __restrict__ csr,
                                                   const float* __restrict__ bias,
                                                   TOut* __restrict__ out,
                                                   int n_nodes) {
    constexpr int LPR = F / 8;       // lanes per row: 16 (F=128) / 8 (F=64)
    constexpr int RPW = 64 / LPR;    // rows per gather instr: 4 / 8
    constexpr int U16 = 16 / RPW;    // in flight, 16-edge batch: 4 / 2
    constexpr int U8  = 8 / RPW;     // in flight, 8-edge batch: 2 / 1
    int wave = threadIdx.x >> 6;
    int lane = threadIdx.x & 63;
    int node = (blockIdx.x << 2) + wave;
    if (node >= n_nodes) return;

    int h  = lane / LPR;             // edge slot group (0..RPW-1)
    int fi = (lane % LPR) * 8;       // feature offset (halves)
    const _Float16* Hf = H + fi;

    int e0 = row_ptr[node];
    int e1 = row_ptr[node + 1];

    float acc[U16][8];
    #pragma unroll
    for (int i = 0; i < U16; ++i)
        #pragma unroll
        for (int j = 0; j < 8; ++j) acc[i][j] = 0.f;

    auto unpack_w = [](unsigned pk) -> float {
        union { unsigned short u; _Float16 h; } cv;
        cv.u = (unsigned short)(pk >> 16);
        return (float)cv.h;
    };

    int e = e0;
    for (; e + 16 <= e1; e += 16) {
        unsigned pk[U16];
        #pragma unroll
        for (int i = 0; i < U16; ++i) pk[i] = csr[e + i * RPW + h];
        #pragma unroll
        for (int i = 0; i < U16; ++i) {
            half8v v = *(const half8v*)(Hf + (size_t)(pk[i] & 0xFFFFu) * F);
            float w = unpack_w(pk[i]);
            #pragma unroll
            for (int j = 0; j < 8; ++j) acc[i][j] = fmaf(w, (float)v[j], acc[i][j]);
        }
    }
    if (e + 8 <= e1) {
        unsigned pk[U8];
        #pragma unroll
        for (int i = 0; i < U8; ++i) pk[i] = csr[e + i * RPW + h];
        #pragma unroll
        for (int i = 0; i < U8; ++i) {
            half8v v = *(const half8v*)(Hf + (size_t)(pk[i] & 0xFFFFu) * F);
            float w = unpack_w(pk[i]);
            #pragma unroll
            for (int j = 0; j < 8; ++j) acc[i][j] = fmaf(w, (float)v[j], acc[i][j]);
        }
        e += 8;
    }
    if (e < e1) {   // exactly 4 remaining (rows padded to x4)
        unsigned pk = (RPW == 4 || h < 4) ? csr[e + h] : 0u;
        half8v v = *(const half8v*)(Hf + (size_t)(pk & 0xFFFFu) * F);
        float w = unpack_w(pk);
        #pragma unroll
        for (int j = 0; j < 8; ++j) acc[0][j] = fmaf(w, (float)v[j], acc[0][j]);
    }

    float t[8];
    #pragma unroll
    for (int j = 0; j < 8; ++j) {
        t[j] = acc[0][j];
        #pragma unroll
        for (int i = 1; i < U16; ++i) t[j] += acc[i][j];
    }
    #pragma unroll
    for (int off = LPR; off < 64; off <<= 1)
        #pragma unroll
        for (int j = 0; j < 8; ++j) t[j] += __shfl_xor(t[j], off);

    if (h == 0) {
        float4 bl = *(const float4*)(bias + fi);
        float4 bh = *(const float4*)(bias + fi + 4);
        float o[8];
        o[0] = fmaxf(t[0] + bl.x, 0.f); o[1] = fmaxf(t[1] + bl.y, 0.f);
        o[2] = fmaxf(t[2] + bl.z, 0.f); o[3] = fmaxf(t[3] + bl.w, 0.f);
        o[4] = fmaxf(t[4] + bh.x, 0.f); o[5] = fmaxf(t[5] + bh.y, 0.f);
        o[6] = fmaxf(t[6] + bh.z, 0.f); o[7] = fmaxf(t[7] + bh.w, 0.f);
        if constexpr (__is_same(TOut, _Float16)) {
            half8v hv;
            #pragma unroll
            for (int j = 0; j < 8; ++j) hv[j] = (_Float16)o[j];
            *(half8v*)(out + (size_t)node * F + fi) = hv;
        } else {
            *(float4*)(out + (size_t)node * F + fi)     = make_float4(o[0], o[1], o[2], o[3]);
            *(float4*)(out + (size_t)node * F + fi + 4) = make_float4(o[4], o[5], o[6], o[7]);
        }
    }
}

// ---------------------------------------------------------------------------

extern "C" void kernel_launch(void* const* d_in, const int* in_sizes, int n_in,
                              void* d_out, int out_size, void* d_ws, size_t ws_size,
                              hipStream_t stream) {
    const float* x  = (const float*)d_in[0];
    const int*   ei = (const int*)d_in[1];     // [2, E] int32
    const float* W1 = (const float*)d_in[2];
    const float* b1 = (const float*)d_in[3];
    const float* W2 = (const float*)d_in[4];
    const float* b2 = (const float*)d_in[5];
    const float* W3 = (const float*)d_in[6];
    const float* b3 = (const float*)d_in[7];

    const int IN_DIM = 256, HID = 128, OUT = 64;
    int n_nodes = in_sizes[0] / IN_DIM;    // 50000 (< 65536 required for u32 pack)
    int n_edges = in_sizes[1] / 2;         // 800000
    int nnz_cap = n_edges + 4 * n_nodes;   // padded (x4) CSR upper bound

    // workspace carve-up
    char* ws = (char*)d_ws;
    size_t off = 0;
    auto carve = [&](size_t bytes) { void* p = ws + off; off += (bytes + 255) & ~(size_t)255; return p; };
    _Float16* Hbuf = (_Float16*)carve((size_t)n_nodes * HID * sizeof(_Float16));
    _Float16* Bbuf = (_Float16*)carve((size_t)n_nodes * HID * sizeof(_Float16));
    _Float16* Bt1  = (_Float16*)carve((size_t)IN_DIM * HID * sizeof(_Float16));
    _Float16* Bt2  = (_Float16*)carve((size_t)HID * HID * sizeof(_Float16));
    _Float16* Bt3  = (_Float16*)carve((size_t)HID * OUT * sizeof(_Float16));
    int*   deg     = (int*)carve((size_t)n_nodes * DSTR * sizeof(int));  // line-padded
    float* dinv    = (float*)carve((size_t)n_nodes * sizeof(float));
    int*   row_ptr = (int*)carve((size_t)(n_nodes + 1) * sizeof(int));
    int*   pos     = (int*)carve((size_t)n_edges * sizeof(int));
    int*   partial = (int*)carve(256 * sizeof(int));
    unsigned* csr  = (unsigned*)carve((size_t)nnz_cap * sizeof(unsigned));
    if (off > ws_size) return;

    float* out = (float*)d_out;

    const int B = 256;
    int nb = (n_nodes + 255) / 256;
    int wtot = IN_DIM * HID + HID * HID + HID * OUT;   // 57344 >= n_nodes

    // ---- graph preprocessing (stream-ordered small kernels) ----
    wcvt_zero_kernel<<<(wtot + B - 1) / B, B, 0, stream>>>(W1, Bt1, W2, Bt2, W3, Bt3,
                                                           deg, n_nodes);
    deg_pos_kernel<<<(n_edges + B - 1) / B, B, 0, stream>>>(ei + n_edges, deg, pos, n_edges);
    scan1_kernel<<<nb, 256, 0, stream>>>(deg, row_ptr, partial, dinv, n_nodes);
    scan2_kernel<<<1, 256, 0, stream>>>(partial, nb);
    scan3_kernel<<<(n_nodes + B - 1) / B, B, 0, stream>>>(partial, row_ptr, n_nodes);

    int spmm_grid = (n_nodes + 3) / 4;
    int gemm_grid = (n_nodes + 127) / 128;
    int fill_grid = (n_edges + 4 * n_nodes + B - 1) / B;

    // ---- fused: fill CSR || layer-1 GEMM (independent work, one dispatch) ----
    fill_gemm1_kernel<<<gemm_grid + fill_grid, 256, 0, stream>>>(
        ei, pos, deg, dinv, row_ptr, csr, n_edges, n_nodes,
        x, Bt1, Hbuf, n_nodes, gemm_grid);

    // ---- layer 1 aggregation ----
    spmm_kernel<128, _Float16><<<spmm_grid, 256, 0, stream>>>(Hbuf, row_ptr, csr, b1, Bbuf, n_nodes);
    // ---- layer 2 ----
    mfma_gemm_kernel<_Float16, 128, 128><<<gemm_grid, 256, 0, stream>>>(Bbuf, Bt2, Hbuf, n_nodes);
    spmm_kernel<128, _Float16><<<spmm_grid, 256, 0, stream>>>(Hbuf, row_ptr, csr, b2, Bbuf, n_nodes);
    // ---- layer 3 ----
    mfma_gemm_kernel<_Float16, 128, 64><<<gemm_grid, 256, 0, stream>>>(Bbuf, Bt3, Hbuf, n_nodes);
    spmm_kernel<64, float><<<spmm_grid, 256, 0, stream>>>(Hbuf, row_ptr, csr, b3, out, n_nodes);
}